// Round 3
// baseline (313.818 us; speedup 1.0000x reference)
//
#include <hip/hip_runtime.h>

// Problem constants (B, L_IN, D) = (4, 4096, 1024)
#define BB 4
#define LL 4096
#define DD 1024
#define SS 64   // number of chunks in the scan
#define TT 64   // chunk length (SS*TT == LL)

typedef __attribute__((ext_vector_type(4))) float  floatx4;
typedef __attribute__((ext_vector_type(8))) short  shortx8;

static __device__ __forceinline__ unsigned short f2bf(float f) {
    unsigned int u = __float_as_uint(f);
    u += 0x7fffu + ((u >> 16) & 1u);           // round-to-nearest-even
    return (unsigned short)(u >> 16);
}
static __device__ __forceinline__ float bf2f(unsigned short h) {
    return __uint_as_float(((unsigned int)h) << 16);
}

// ---------------- merged f32 -> bf16 cast (inputs + Wi + Wo) ----------------
#define NIN4 (BB * LL * DD / 4)          // 4194304
#define NW4  (2 * DD * DD / 4)           // 524288
__global__ void cast_all_kernel(const float4* __restrict__ s_in, ushort4* __restrict__ d_inb,
                                const float4* __restrict__ s_wi, ushort4* __restrict__ d_wib,
                                const float4* __restrict__ s_wo, ushort4* __restrict__ d_wob) {
    int i = blockIdx.x * blockDim.x + threadIdx.x;
    const float4* s; ushort4* d; int j;
    if (i < NIN4)                 { s = s_in; d = d_inb; j = i; }
    else if (i < NIN4 + NW4)      { s = s_wi; d = d_wib; j = i - NIN4; }
    else                          { s = s_wo; d = d_wob; j = i - NIN4 - NW4; }
    float4 v = s[j];
    ushort4 o;
    o.x = f2bf(v.x); o.y = f2bf(v.y); o.z = f2bf(v.z); o.w = f2bf(v.w);
    d[j] = o;
}

// ---------------- bf16 GEMM: C[M,N] = A[M,K] * B[N,K]^T + bias ----------------
// 256x256 tile, BK=64, 512 threads = 8 waves (2M x 4N), per-wave 128x64 output.
// 4-phase K-tile with sched_group_barrier-pinned {MFMA, ds_read} interleave:
// each phase's read-ahead ds_reads issue in the matrix-pipe backpressure slots
// of its MFMA cluster, so the LDS drain hides under MFMA. Reads balanced
// 4/8/4/8 per phase; one counted vmcnt(2) per K-tile at ph3-top (retires
// exactly through B0(t+1), enabling ph3's next-tile B0 read-ahead).
//
// Register rotation: af (A-half, shared A0/A1, WAR resolved by kk-major load
// order: af[il][kk] write k legal after MFMA 2k); b0f[parity] (B0 of tile t in
// b0f[t&1], next tile's B0 loaded into b0f[~t&1] at ph3); b1f (B1, loaded at
// ph1, free since prev ph4).
//
// Hazard invariants (same as r2, re-verified):
//  - every STAGE overwriting region R is issued after a barrier that follows
//    all waves' lgkmcnt(0)-drain of R's last ds_reads (one full phase gap).
//  - vmcnt(2)+BAR at ph3-top: per-wave outstanding GLLs at that point =
//    [S(t-1,p2),S(t-1,p3),S(t-1,p4),S(t,p1),S(t,p2)] = 10; keeping newest 2
//    retires through S(t,p1)=B0(t+1); barrier makes all waves' stores visible
//    before ph3's LOAD of B0(t+1) and ph4's LOAD of A0(t+1).
template<int K, int NT, int EPI>
__global__ __launch_bounds__(512, 2)
void gemm256(const unsigned short* __restrict__ A,
             const unsigned short* __restrict__ B,
             const float* __restrict__ bias,
             void* __restrict__ Cp) {
    constexpr int N   = NT * 256;
    constexpr int NKT = K / 64;            // 16 or 32 here (even)
    __shared__ __align__(16) short As[2][256 * 64];   // 64 KB
    __shared__ __align__(16) short Bs[2][256 * 64];   // 64 KB

    const int tid = threadIdx.x;
    const int blk = blockIdx.x;
    const int xcd = blk & 7;
    const int i2  = blk >> 3;
    const int tileM = ((i2 / NT) * 8 + xcd) * 256;
    const int tileN = (i2 % NT) * 256;

    const int lane   = tid & 63;
    const int wave   = tid >> 6;
    const int wave_m = wave >> 2;          // 0..1
    const int wave_n = wave & 3;           // 0..3
    const int r16    = lane & 15;
    const int quad   = lane >> 4;
    const int slotx  = r16 & 7;
    const int wmRow  = wave_m * 64 + r16;
    const int wnRow  = wave_n * 32 + r16;

    const int srow = tid >> 3;                         // 0..63
    const int scol = ((tid & 7) ^ (srow & 7)) * 8;     // pre-swizzled k offset (shorts)
    const int ldsChunkBase = (tid & ~63) * 8;          // shorts
    const size_t aOff = (size_t)(tileM + srow) * K + scol;
    const size_t bOff = (size_t)(tileN + srow) * K + scol;

    floatx4 acc[8][4] = {};
    shortx8 af[4][2], b0f[2][2][2], b1f[2][2];

#define GLL(SRC, DST) __builtin_amdgcn_global_load_lds( \
        (const __attribute__((address_space(1))) void*)(SRC), \
        (__attribute__((address_space(3))) void*)(DST), 16, 0, 0)
#define STAGE_A(BUF, H, KT) do { \
    GLL(A + aOff + (size_t)((H) * 128) * K + (KT) * 64,      &As[(BUF)][(H) * 8192 + ldsChunkBase]); \
    GLL(A + aOff + (size_t)((H) * 128 + 64) * K + (KT) * 64, &As[(BUF)][(H) * 8192 + 4096 + ldsChunkBase]); \
} while (0)
#define STAGE_B(BUF, H, KT) do { \
    GLL(B + bOff + (size_t)((H) * 128) * K + (KT) * 64,      &Bs[(BUF)][(H) * 8192 + ldsChunkBase]); \
    GLL(B + bOff + (size_t)((H) * 128 + 64) * K + (KT) * 64, &Bs[(BUF)][(H) * 8192 + 4096 + ldsChunkBase]); \
} while (0)
// kk-major load order (WAR-feasible for the {2 MFMA, 1 DS} interleave)
#define LOAD_A(BUF, MH) do { \
    _Pragma("unroll") for (int kk = 0; kk < 2; ++kk) \
    _Pragma("unroll") for (int il = 0; il < 4; ++il) \
        af[il][kk] = *(const shortx8*)&As[(BUF)][((MH) * 128 + wmRow + il * 16) * 64 + ((kk * 4 + quad) ^ slotx) * 8]; \
} while (0)
#define LOAD_B(BUF, NH, DST) do { \
    _Pragma("unroll") for (int kk = 0; kk < 2; ++kk) \
    _Pragma("unroll") for (int jl = 0; jl < 2; ++jl) \
        DST[jl][kk] = *(const shortx8*)&Bs[(BUF)][((NH) * 128 + wnRow + jl * 16) * 64 + ((kk * 4 + quad) ^ slotx) * 8]; \
} while (0)
#define MFMAQ(MH, NH, BF) do { \
    _Pragma("unroll") for (int kk = 0; kk < 2; ++kk) \
    _Pragma("unroll") for (int il = 0; il < 4; ++il) \
    _Pragma("unroll") for (int jl = 0; jl < 2; ++jl) \
        acc[(MH) * 4 + il][(NH) * 2 + jl] = __builtin_amdgcn_mfma_f32_16x16x32_bf16( \
            af[il][kk], BF[jl][kk], acc[(MH) * 4 + il][(NH) * 2 + jl], 0, 0, 0); \
} while (0)
#define BAR()   __builtin_amdgcn_s_barrier()
#define LGKM0() asm volatile("s_waitcnt lgkmcnt(0)" ::: "memory")
// sched_group_barrier masks: MFMA=0x8, DS_READ=0x100
#define SGB(M, NN) __builtin_amdgcn_sched_group_barrier(M, NN, 0)
#define S41() do { SGB(0x8, 4); SGB(0x100, 1); } while (0)
#define S21() do { SGB(0x8, 2); SGB(0x100, 1); } while (0)
#define PAT41() do { S41(); S41(); S41(); S41(); } while (0)                      // 16 MFMA + 4 DS
#define PAT21() do { S21(); S21(); S21(); S21(); S21(); S21(); S21(); S21(); } while (0) // 16 MFMA + 8 DS

#define TILE(P, T1, T2) do { \
    /* ---- ph1: Q(0,0) = af(A0) x b0f[P]; read-ahead B1 -> b1f ---- */ \
    BAR(); LGKM0(); \
    STAGE_B((P) ^ 1, 0, (T1)); \
    __builtin_amdgcn_s_setprio(1); \
    MFMAQ(0, 0, b0f[(P)]); \
    LOAD_B((P), 1, b1f); \
    PAT41(); \
    __builtin_amdgcn_s_setprio(0); \
    /* ---- ph2: Q(0,1) = af(A0) x b1f; read-ahead A1 -> af ---- */ \
    BAR(); LGKM0(); \
    STAGE_A((P), 0, (T2)); \
    __builtin_amdgcn_s_setprio(1); \
    MFMAQ(0, 1, b1f); \
    LOAD_A((P), 1); \
    PAT21(); \
    __builtin_amdgcn_s_setprio(0); \
    /* ---- ph3: Q(1,0) = af(A1) x b0f[P]; read-ahead B0(t+1) -> b0f[P^1] ---- */ \
    asm volatile("s_waitcnt vmcnt(2)" ::: "memory"); \
    BAR(); LGKM0(); \
    STAGE_B((P), 1, (T2)); \
    __builtin_amdgcn_s_setprio(1); \
    MFMAQ(1, 0, b0f[(P)]); \
    LOAD_B((P) ^ 1, 0, b0f[(P) ^ 1]); \
    PAT41(); \
    __builtin_amdgcn_s_setprio(0); \
    /* ---- ph4: Q(1,1) = af(A1) x b1f; read-ahead A0(t+1) -> af ---- */ \
    BAR(); \
    STAGE_A((P), 1, (T2)); \
    __builtin_amdgcn_s_setprio(1); \
    MFMAQ(1, 1, b1f); \
    LOAD_A((P) ^ 1, 0); \
    PAT21(); \
    __builtin_amdgcn_s_setprio(0); \
} while (0)

    // prologue: tile0 (A0,B0,B1,A1) + A0(1),B1(1),A1(1) = 14 GLLs
    STAGE_A(0, 0, 0);
    STAGE_B(0, 0, 0);
    STAGE_B(0, 1, 0);
    STAGE_A(0, 1, 0);
    STAGE_A(1, 0, 1);
    STAGE_B(1, 1, 1);
    STAGE_A(1, 1, 1);
    asm volatile("s_waitcnt vmcnt(6)" ::: "memory");   // tile0 landed; 6 in flight
    BAR();
    LOAD_A(0, 0);          // af  = A0(0)
    LOAD_B(0, 0, b0f[0]);  // b0f[0] = B0(0)

    for (int t = 0; t < NKT; t += 2) {
        const int e1 = (t + 1 < NKT) ? t + 1 : NKT - 1;   // clamped tail keeps
        const int e2 = (t + 2 < NKT) ? t + 2 : NKT - 1;   // vmcnt counts uniform
        TILE(0, e1, e2);
        const int o1 = (t + 2 < NKT) ? t + 2 : NKT - 1;
        const int o2 = (t + 3 < NKT) ? t + 3 : NKT - 1;
        TILE(1, o1, o2);
    }
    asm volatile("s_waitcnt vmcnt(0) lgkmcnt(0)" ::: "memory");  // drain tail

    // epilogue: C row = tileM + (i>>2)*128 + wave_m*64 + (i&3)*16 + quad*4 + r
    //           C col = tileN + (j>>1)*128 + wave_n*32 + (j&1)*16 + r16
#pragma unroll
    for (int i = 0; i < 8; ++i) {
        const int row0 = tileM + (i >> 2) * 128 + wave_m * 64 + (i & 3) * 16 + quad * 4;
#pragma unroll
        for (int j = 0; j < 4; ++j) {
            const int col = tileN + (j >> 1) * 128 + wave_n * 32 + (j & 1) * 16 + r16;
            const float bv = bias[col];
#pragma unroll
            for (int r = 0; r < 4; ++r) {
                float v = acc[i][j][r] + bv;
                if (EPI == 0) {
                    ((unsigned short*)Cp)[(size_t)(row0 + r) * N + col] = f2bf(v);
                } else {
                    ((float*)Cp)[(size_t)(row0 + r) * N + col] = fmaxf(v, 0.0f);
                }
            }
        }
    }
#undef GLL
#undef STAGE_A
#undef STAGE_B
#undef LOAD_A
#undef LOAD_B
#undef MFMAQ
#undef BAR
#undef LGKM0
#undef SGB
#undef S41
#undef S21
#undef PAT41
#undef PAT21
#undef TILE
}

// ---------------- scan phase A: per-chunk local end values (2 ch/thread) ----------------
// u: bf16 [B*L, 2D] (re/im interleaved per channel). Eend: [SS][B*D] float2.
__global__ __launch_bounds__(256)
void scanA(const unsigned short* __restrict__ u,
           const float* __restrict__ plog,
           float2* __restrict__ Eend) {
    const int d0 = (blockIdx.x * 256 + threadIdx.x) * 2;
    const int c = blockIdx.y, b = blockIdx.z;
    const float v0  = expf(plog[d0]),      v1  = expf(plog[d0 + 1]);
    const float th0 = expf(plog[DD + d0]), th1 = expf(plog[DD + d0 + 1]);
    const float a0 = expf(-v0), a1 = expf(-v1);
    const float lr0 = a0 * cosf(th0), li0 = a0 * sinf(th0);
    const float lr1 = a1 * cosf(th1), li1 = a1 * sinf(th1);
    float zr0 = 0.f, zi0 = 0.f, zr1 = 0.f, zi1 = 0.f;
    const unsigned short* up = u + (size_t)(b * LL + c * TT) * (2 * DD) + 2 * d0;
#pragma unroll 4
    for (int tl = 0; tl < TT; ++tl) {
        uint2 pr = *(const uint2*)up;
        float xr0 = bf2f((unsigned short)(pr.x & 0xffffu));
        float xi0 = bf2f((unsigned short)(pr.x >> 16));
        float xr1 = bf2f((unsigned short)(pr.y & 0xffffu));
        float xi1 = bf2f((unsigned short)(pr.y >> 16));
        float t;
        t = lr0 * zr0 - li0 * zi0 + xr0; zi0 = lr0 * zi0 + li0 * zr0 + xi0; zr0 = t;
        t = lr1 * zr1 - li1 * zi1 + xr1; zi1 = lr1 * zi1 + li1 * zr1 + xi1; zr1 = t;
        up += 2 * DD;
    }
    *(float4*)&Eend[(size_t)c * (BB * DD) + b * DD + d0] =
        make_float4(zr0, zi0, zr1, zi1);
}

// ---------------- scan phase C: carry prefix + fix-up + gamma (2 ch/thread) ----------------
// xr layout: [B*L, 2D] with col d = gamma*Re(y), col DD+d = gamma*Im(y)
__global__ __launch_bounds__(256)
void scanC(const unsigned short* __restrict__ u,
           const float* __restrict__ plog,
           const float2* __restrict__ Eend,
           unsigned short* __restrict__ xr) {
    const int d0 = (blockIdx.x * 256 + threadIdx.x) * 2;
    const int c = blockIdx.y, b = blockIdx.z;
    const float v0  = expf(plog[d0]),      v1  = expf(plog[d0 + 1]);
    const float th0 = expf(plog[DD + d0]), th1 = expf(plog[DD + d0 + 1]);
    const float g0  = expf(plog[2 * DD + d0]), g1 = expf(plog[2 * DD + d0 + 1]);
    const float a0 = expf(-v0), a1 = expf(-v1);
    const float lr0 = a0 * cosf(th0), li0 = a0 * sinf(th0);
    const float lr1 = a1 * cosf(th1), li1 = a1 * sinf(th1);

    // carry into chunk c: prefix over earlier chunks with Lambda = lambda^TT
    const float aT0 = expf(-(float)TT * v0), aT1 = expf(-(float)TT * v1);
    const float Lr0 = aT0 * cosf((float)TT * th0), Li0 = aT0 * sinf((float)TT * th0);
    const float Lr1 = aT1 * cosf((float)TT * th1), Li1 = aT1 * sinf((float)TT * th1);
    float yr0 = 0.f, yi0 = 0.f, yr1 = 0.f, yi1 = 0.f;
    for (int cc = 0; cc < c; ++cc) {
        float4 e = *(const float4*)&Eend[(size_t)cc * (BB * DD) + b * DD + d0];
        float t;
        t = Lr0 * yr0 - Li0 * yi0 + e.x; yi0 = Lr0 * yi0 + Li0 * yr0 + e.y; yr0 = t;
        t = Lr1 * yr1 - Li1 * yi1 + e.z; yi1 = Lr1 * yi1 + Li1 * yr1 + e.w; yr1 = t;
    }

    const unsigned short* up = u + (size_t)(b * LL + c * TT) * (2 * DD) + 2 * d0;
    unsigned short* xp = xr + (size_t)(b * LL + c * TT) * (2 * DD) + d0;
#pragma unroll 4
    for (int tl = 0; tl < TT; ++tl) {
        uint2 pr = *(const uint2*)up;
        float xr0 = bf2f((unsigned short)(pr.x & 0xffffu));
        float xi0 = bf2f((unsigned short)(pr.x >> 16));
        float xr1 = bf2f((unsigned short)(pr.y & 0xffffu));
        float xi1 = bf2f((unsigned short)(pr.y >> 16));
        float t;
        t = lr0 * yr0 - li0 * yi0 + xr0; yi0 = lr0 * yi0 + li0 * yr0 + xi0; yr0 = t;
        t = lr1 * yr1 - li1 * yi1 + xr1; yi1 = lr1 * yi1 + li1 * yr1 + xi1; yr1 = t;
        *(unsigned int*)&xp[0]  = (unsigned int)f2bf(g0 * yr0) |
                                  ((unsigned int)f2bf(g1 * yr1) << 16);
        *(unsigned int*)&xp[DD] = (unsigned int)f2bf(g0 * yi0) |
                                  ((unsigned int)f2bf(g1 * yi1) << 16);
        up += 2 * DD;
        xp += 2 * DD;
    }
}

extern "C" void kernel_launch(void* const* d_in, const int* in_sizes, int n_in,
                              void* d_out, int out_size, void* d_ws, size_t ws_size,
                              hipStream_t stream) {
    const float* inputs = (const float*)d_in[0];   // B*L*D = 16777216
    const float* Wi     = (const float*)d_in[1];   // 2D*D  = 2097152
    const float* bi     = (const float*)d_in[2];   // 2D
    const float* Wo     = (const float*)d_in[3];   // D*2D  = 2097152
    const float* bo     = (const float*)d_in[4];   // D
    const float* plog   = (const float*)d_in[5];   // 3*D
    float* out = (float*)d_out;

    const size_t M = (size_t)BB * LL;              // 16384
    unsigned short* u_bf  = (unsigned short*)d_ws;             // M*2D bf16  (64 MB)
    unsigned short* xr_bf = u_bf  + M * 2 * DD;                // M*2D bf16  (64 MB)
    unsigned short* in_bf = xr_bf + M * 2 * DD;                // M*D  bf16  (32 MB)
    unsigned short* Wi_bf = in_bf + M * DD;                    // 2D*D bf16  (4 MB)
    unsigned short* Wo_bf = Wi_bf + (size_t)2 * DD * DD;       // D*2D bf16  (4 MB)
    float2* Eend = (float2*)(Wo_bf + (size_t)2 * DD * DD);     // SS*B*D f32x2 (2 MB)

    // merged bf16 casts (inputs + Wi + Wo) in one dispatch
    {
        int total4 = NIN4 + 2 * NW4;
        cast_all_kernel<<<total4 / 256, 256, 0, stream>>>(
            (const float4*)inputs, (ushort4*)in_bf,
            (const float4*)Wi,     (ushort4*)Wi_bf,
            (const float4*)Wo,     (ushort4*)Wo_bf);
    }

    // GEMM1: u[M, 2D] = in_bf[M, D] @ Wi^T + bi   (bf16 out), N=2048 -> NT=8
    gemm256<DD, 8, 0><<<(M / 256) * 8, 512, 0, stream>>>(
        in_bf, Wi_bf, bi, (void*)u_bf);

    // scan (2-pass chunked; carries computed inline in scanC), 2 channels/thread
    scanA<<<dim3(DD / 512, SS, BB), 256, 0, stream>>>(u_bf, plog, Eend);
    scanC<<<dim3(DD / 512, SS, BB), 256, 0, stream>>>(u_bf, plog, Eend, xr_bf);

    // GEMM2: out[M, D] = relu(xr[M, 2D] @ Wo^T + bo)  (f32 out), N=1024 -> NT=4
    gemm256<2 * DD, 4, 1><<<(M / 256) * 4, 512, 0, stream>>>(
        xr_bf, Wo_bf, bo, (void*)out);
}

// Round 4
// 294.865 us; speedup vs baseline: 1.0643x; 1.0643x over previous
//
#include <hip/hip_runtime.h>

// Problem constants (B, L_IN, D) = (4, 4096, 1024)
#define BB 4
#define LL 4096
#define DD 1024
#define SS 128  // number of chunks in the scan
#define TT 32   // chunk length (SS*TT == LL)

typedef __attribute__((ext_vector_type(4))) float  floatx4;
typedef __attribute__((ext_vector_type(8))) short  shortx8;

static __device__ __forceinline__ unsigned short f2bf(float f) {
    unsigned int u = __float_as_uint(f);
    u += 0x7fffu + ((u >> 16) & 1u);           // round-to-nearest-even
    return (unsigned short)(u >> 16);
}
static __device__ __forceinline__ float bf2f(unsigned short h) {
    return __uint_as_float(((unsigned int)h) << 16);
}

// ---------------- merged f32 -> bf16 cast (inputs + Wi + Wo) ----------------
#define NIN4 (BB * LL * DD / 4)          // 4194304
#define NW4  (2 * DD * DD / 4)           // 524288
__global__ void cast_all_kernel(const float4* __restrict__ s_in, ushort4* __restrict__ d_inb,
                                const float4* __restrict__ s_wi, ushort4* __restrict__ d_wib,
                                const float4* __restrict__ s_wo, ushort4* __restrict__ d_wob) {
    int i = blockIdx.x * blockDim.x + threadIdx.x;
    const float4* s; ushort4* d; int j;
    if (i < NIN4)                 { s = s_in; d = d_inb; j = i; }
    else if (i < NIN4 + NW4)      { s = s_wi; d = d_wib; j = i - NIN4; }
    else                          { s = s_wo; d = d_wob; j = i - NIN4 - NW4; }
    float4 v = s[j];
    ushort4 o;
    o.x = f2bf(v.x); o.y = f2bf(v.y); o.z = f2bf(v.z); o.w = f2bf(v.w);
    d[j] = o;
}

// ---------------- bf16 GEMM: C[M,N] = A[M,K] * B[N,K]^T + bias ----------------
// 256x256 tile, BK=64, 512 threads = 8 waves (2M x 4N), per-wave 128x64 output.
// READ-AHEAD 4-phase schedule (best measured r2 variant): each phase issues the
// NEXT phase's ds_reads AFTER its MFMA cluster, so read drain hides under MFMA
// + barrier; one raw s_barrier per phase; counted vmcnt(4) once per K-tile.
//
// Hazard proof (semantic, no timing assumptions). R(p) = reads pending at
// phase p top (issued end of p-1); S(p) = region staged in phase p.
//   R(ph1)={A0,B0}(cb)  R(ph2)={B1(cb)}  R(ph3)={A1(cb)}  R(ph4)={}
//   S(ph1)=B0(cb^1,t+1) S(ph2)=A0(cb,t+2) S(ph3)=B1(cb,t+2) S(ph4)=A1(cb,t+2)
// 1) S(p) ∩ R(p) = ∅ and S(p) ∩ R(p+1) = ∅ for all p.
// 2) Every S(p) overwriting a previously-read region is issued after a barrier
//    whose arrival implies all waves retired those reads via lgkmcnt(0).
// 3) vmcnt(4) before bar4 retires everything through S(ph1)=B0(t+1);
//    end-of-ph4 reads {A0,B0}(cb^1,t+1) are issued after bar4.
//
// LDS chunk swizzle (verified, 0 bank conflicts): within each 128-row
// half-tile, chunk q holds row=q>>3, k8=(q&7)^(row&7); reads XOR with r16&7.
template<int K, int NT, int EPI>
__global__ __launch_bounds__(512, 2)
void gemm256(const unsigned short* __restrict__ A,
             const unsigned short* __restrict__ B,
             const float* __restrict__ bias,
             void* __restrict__ Cp) {
    constexpr int N   = NT * 256;
    constexpr int NKT = K / 64;            // 16 or 32 here
    __shared__ __align__(16) short As[2][256 * 64];   // 64 KB
    __shared__ __align__(16) short Bs[2][256 * 64];   // 64 KB

    const int tid = threadIdx.x;
    const int blk = blockIdx.x;
    const int xcd = blk & 7;
    const int i2  = blk >> 3;
    const int tileM = ((i2 / NT) * 8 + xcd) * 256;
    const int tileN = (i2 % NT) * 256;

    const int lane   = tid & 63;
    const int wave   = tid >> 6;
    const int wave_m = wave >> 2;          // 0..1
    const int wave_n = wave & 3;           // 0..3
    const int r16    = lane & 15;
    const int quad   = lane >> 4;
    const int slotx  = r16 & 7;
    const int wmRow  = wave_m * 64 + r16;
    const int wnRow  = wave_n * 32 + r16;

    const int srow = tid >> 3;                         // 0..63
    const int scol = ((tid & 7) ^ (srow & 7)) * 8;     // pre-swizzled k offset (shorts)
    const int ldsChunkBase = (tid & ~63) * 8;          // shorts
    const size_t aOff = (size_t)(tileM + srow) * K + scol;
    const size_t bOff = (size_t)(tileN + srow) * K + scol;

    floatx4 acc[8][4] = {};
    shortx8 af[4][2], bf0v[2][2], bf1v[2][2];

#define GLL(SRC, DST) __builtin_amdgcn_global_load_lds( \
        (const __attribute__((address_space(1))) void*)(SRC), \
        (__attribute__((address_space(3))) void*)(DST), 16, 0, 0)
#define STAGE_A(BUF, H, KT) do { \
    GLL(A + aOff + (size_t)((H) * 128) * K + (KT) * 64,      &As[BUF][(H) * 8192 + ldsChunkBase]); \
    GLL(A + aOff + (size_t)((H) * 128 + 64) * K + (KT) * 64, &As[BUF][(H) * 8192 + 4096 + ldsChunkBase]); \
} while (0)
#define STAGE_B(BUF, H, KT) do { \
    GLL(B + bOff + (size_t)((H) * 128) * K + (KT) * 64,      &Bs[BUF][(H) * 8192 + ldsChunkBase]); \
    GLL(B + bOff + (size_t)((H) * 128 + 64) * K + (KT) * 64, &Bs[BUF][(H) * 8192 + 4096 + ldsChunkBase]); \
} while (0)
#define LOAD_A(BUF, MH) do { \
    _Pragma("unroll") for (int il = 0; il < 4; ++il) \
    _Pragma("unroll") for (int kk = 0; kk < 2; ++kk) \
        af[il][kk] = *(const shortx8*)&As[BUF][((MH) * 128 + wmRow + il * 16) * 64 + ((kk * 4 + quad) ^ slotx) * 8]; \
} while (0)
#define LOAD_B(BUF, NH, DST) do { \
    _Pragma("unroll") for (int jl = 0; jl < 2; ++jl) \
    _Pragma("unroll") for (int kk = 0; kk < 2; ++kk) \
        DST[jl][kk] = *(const shortx8*)&Bs[BUF][((NH) * 128 + wnRow + jl * 16) * 64 + ((kk * 4 + quad) ^ slotx) * 8]; \
} while (0)
#define MFMAQ(MH, NH, BF) do { \
    __builtin_amdgcn_s_setprio(1); \
    _Pragma("unroll") for (int kk = 0; kk < 2; ++kk) \
    _Pragma("unroll") for (int il = 0; il < 4; ++il) \
    _Pragma("unroll") for (int jl = 0; jl < 2; ++jl) \
        acc[(MH) * 4 + il][(NH) * 2 + jl] = __builtin_amdgcn_mfma_f32_16x16x32_bf16( \
            af[il][kk], BF[jl][kk], acc[(MH) * 4 + il][(NH) * 2 + jl], 0, 0, 0); \
    __builtin_amdgcn_s_setprio(0); \
} while (0)
#define BAR()  __builtin_amdgcn_s_barrier()
#define LGKM0() asm volatile("s_waitcnt lgkmcnt(0)" ::: "memory")

    // prologue: tile0 (A0,B0,B1,A1) + A0(1),B1(1),A1(1) = 14 GLLs
    STAGE_A(0, 0, 0);
    STAGE_B(0, 0, 0);
    STAGE_B(0, 1, 0);
    STAGE_A(0, 1, 0);
    STAGE_A(1, 0, 1);
    STAGE_B(1, 1, 1);
    STAGE_A(1, 1, 1);
    asm volatile("s_waitcnt vmcnt(6)" ::: "memory");   // tile0 landed; 6 in flight
    BAR();
    // pre-issue ph1(t=0) operands
    LOAD_A(0, 0);
    LOAD_B(0, 0, bf0v);

#pragma unroll 2
    for (int t = 0; t < NKT; ++t) {
        const int cb = t & 1;
        const int t1 = (t + 1 < NKT) ? t + 1 : NKT - 1;   // clamped tail: keeps
        const int t2 = (t + 2 < NKT) ? t + 2 : NKT - 1;   // vmcnt counts uniform
        // ---- phase 1: Q(0,0) ----
        BAR();
        LGKM0();                       // {A0,B0}(cb) reads retired (drained under prev MFMA)
        STAGE_B(cb ^ 1, 0, t1);
        MFMAQ(0, 0, bf0v);
        LOAD_B(cb, 1, bf1v);           // read-ahead for ph2
        // ---- phase 2: Q(0,1) ----
        BAR();
        LGKM0();
        STAGE_A(cb, 0, t2);            // safe: A0 reads retired by all waves at ph1 lgkm
        MFMAQ(0, 1, bf1v);
        LOAD_A(cb, 1);                 // read-ahead for ph3
        // ---- phase 3: Q(1,0) ----
        BAR();
        LGKM0();
        STAGE_B(cb, 1, t2);            // safe: B1 reads retired at ph2 lgkm
        MFMAQ(1, 0, bf0v);
        // ---- phase 4: Q(1,1) ----
        asm volatile("s_waitcnt vmcnt(4)" ::: "memory");  // retires through B0(t+1)
        BAR();
        STAGE_A(cb, 1, t2);            // safe: A1 reads retired at ph3 lgkm, after bar4
        MFMAQ(1, 1, bf1v);
        LOAD_A(cb ^ 1, 0);             // read-ahead for next tile's ph1
        LOAD_B(cb ^ 1, 0, bf0v);       // (tile t+1 fully landed via vmcnt(4)+bar)
    }
    asm volatile("s_waitcnt vmcnt(0) lgkmcnt(0)" ::: "memory");  // drain tail

    // epilogue: C row = tileM + (i>>2)*128 + wave_m*64 + (i&3)*16 + quad*4 + r
    //           C col = tileN + (j>>1)*128 + wave_n*32 + (j&1)*16 + r16
#pragma unroll
    for (int i = 0; i < 8; ++i) {
        const int row0 = tileM + (i >> 2) * 128 + wave_m * 64 + (i & 3) * 16 + quad * 4;
#pragma unroll
        for (int j = 0; j < 4; ++j) {
            const int col = tileN + (j >> 1) * 128 + wave_n * 32 + (j & 1) * 16 + r16;
            const float bv = bias[col];
#pragma unroll
            for (int r = 0; r < 4; ++r) {
                float v = acc[i][j][r] + bv;
                if (EPI == 0) {
                    ((unsigned short*)Cp)[(size_t)(row0 + r) * N + col] = f2bf(v);
                } else {
                    ((float*)Cp)[(size_t)(row0 + r) * N + col] = fmaxf(v, 0.0f);
                }
            }
        }
    }
#undef GLL
#undef STAGE_A
#undef STAGE_B
#undef LOAD_A
#undef LOAD_B
#undef MFMAQ
#undef BAR
#undef LGKM0
}

// ---------------- scan phase A: per-chunk local end values (1 ch/thread) ----------------
// u: bf16 [B*L, 2D] (re/im interleaved per channel). Eend: [SS][B*D] float2.
// Grid (DD/256, SS, BB) = (4,128,4): 8192 waves = 8/SIMD for latency hiding.
__global__ __launch_bounds__(256)
void scanA(const unsigned short* __restrict__ u,
           const float* __restrict__ plog,
           float2* __restrict__ Eend) {
    const int d = blockIdx.x * 256 + threadIdx.x;
    const int c = blockIdx.y, b = blockIdx.z;
    const float v  = expf(plog[d]);
    const float th = expf(plog[DD + d]);
    const float a  = expf(-v);
    const float lr = a * cosf(th), li = a * sinf(th);
    float zr = 0.f, zi = 0.f;
    const unsigned short* up = u + (size_t)(b * LL + c * TT) * (2 * DD) + 2 * d;
#pragma unroll 8
    for (int tl = 0; tl < TT; ++tl) {
        unsigned int pr = *(const unsigned int*)up;
        float xr = bf2f((unsigned short)(pr & 0xffffu));
        float xi = bf2f((unsigned short)(pr >> 16));
        float t = lr * zr - li * zi + xr;
        zi = lr * zi + li * zr + xi;
        zr = t;
        up += 2 * DD;
    }
    Eend[(size_t)c * (BB * DD) + b * DD + d] = make_float2(zr, zi);
}

// ---------------- scan phase B: in-place exclusive carry prefix over chunks ----
// E[c][b][d] : on entry = chunk-local end values; on exit = carry INTO chunk c
// (prefix of chunks < c, combined with Lambda = lambda^TT).
// BB*DD = 4096 threads total; independent loads pipeline under unroll.
__global__ __launch_bounds__(256)
void scanB(const float* __restrict__ plog, float2* __restrict__ E) {
    const int i = blockIdx.x * 256 + threadIdx.x;   // i = b*DD + d
    const int d = i & (DD - 1);
    const float v  = expf(plog[d]);
    const float th = expf(plog[DD + d]);
    const float aT = expf(-(float)TT * v);
    const float Lr = aT * cosf((float)TT * th), Li = aT * sinf((float)TT * th);
    float yr = 0.f, yi = 0.f;
    float2* p = E + i;
#pragma unroll 8
    for (int c = 0; c < SS; ++c) {
        float2 e = *p;
        *p = make_float2(yr, yi);      // exclusive prefix (safe in-place: 1 thread per [*][i])
        float t = Lr * yr - Li * yi + e.x;
        yi = Lr * yi + Li * yr + e.y;
        yr = t;
        p += BB * DD;
    }
}

// ---------------- scan phase C: local scan from carry + gamma (1 ch/thread) ----
// xr layout: [B*L, 2D] with col d = gamma*Re(y), col DD+d = gamma*Im(y)
__global__ __launch_bounds__(256)
void scanC(const unsigned short* __restrict__ u,
           const float* __restrict__ plog,
           const float2* __restrict__ Carry,
           unsigned short* __restrict__ xr) {
    const int d = blockIdx.x * 256 + threadIdx.x;
    const int c = blockIdx.y, b = blockIdx.z;
    const float v  = expf(plog[d]);
    const float th = expf(plog[DD + d]);
    const float g  = expf(plog[2 * DD + d]);
    const float a  = expf(-v);
    const float lr = a * cosf(th), li = a * sinf(th);
    const float2 cy = Carry[(size_t)c * (BB * DD) + b * DD + d];
    float yr = cy.x, yi = cy.y;
    const unsigned short* up = u + (size_t)(b * LL + c * TT) * (2 * DD) + 2 * d;
    unsigned short* xp = xr + (size_t)(b * LL + c * TT) * (2 * DD) + d;
#pragma unroll 8
    for (int tl = 0; tl < TT; ++tl) {
        unsigned int pr = *(const unsigned int*)up;
        float xrv = bf2f((unsigned short)(pr & 0xffffu));
        float xiv = bf2f((unsigned short)(pr >> 16));
        float t = lr * yr - li * yi + xrv;
        yi = lr * yi + li * yr + xiv;
        yr = t;
        xp[0]  = f2bf(g * yr);
        xp[DD] = f2bf(g * yi);
        up += 2 * DD;
        xp += 2 * DD;
    }
}

extern "C" void kernel_launch(void* const* d_in, const int* in_sizes, int n_in,
                              void* d_out, int out_size, void* d_ws, size_t ws_size,
                              hipStream_t stream) {
    const float* inputs = (const float*)d_in[0];   // B*L*D = 16777216
    const float* Wi     = (const float*)d_in[1];   // 2D*D  = 2097152
    const float* bi     = (const float*)d_in[2];   // 2D
    const float* Wo     = (const float*)d_in[3];   // D*2D  = 2097152
    const float* bo     = (const float*)d_in[4];   // D
    const float* plog   = (const float*)d_in[5];   // 3*D
    float* out = (float*)d_out;

    const size_t M = (size_t)BB * LL;              // 16384
    unsigned short* u_bf  = (unsigned short*)d_ws;             // M*2D bf16  (64 MB)
    unsigned short* xr_bf = u_bf  + M * 2 * DD;                // M*2D bf16  (64 MB)
    unsigned short* in_bf = xr_bf + M * 2 * DD;                // M*D  bf16  (32 MB)
    unsigned short* Wi_bf = in_bf + M * DD;                    // 2D*D bf16  (4 MB)
    unsigned short* Wo_bf = Wi_bf + (size_t)2 * DD * DD;       // D*2D bf16  (4 MB)
    // Eend/Carry (SS*B*D float2 = 4 MB) aliases in_bf: in_bf is dead after
    // GEMM1 completes, and scanA (the first Eend writer) runs after GEMM1.
    float2* Eend = (float2*)in_bf;

    // merged bf16 casts (inputs + Wi + Wo) in one dispatch
    {
        int total4 = NIN4 + 2 * NW4;
        cast_all_kernel<<<total4 / 256, 256, 0, stream>>>(
            (const float4*)inputs, (ushort4*)in_bf,
            (const float4*)Wi,     (ushort4*)Wi_bf,
            (const float4*)Wo,     (ushort4*)Wo_bf);
    }

    // GEMM1: u[M, 2D] = in_bf[M, D] @ Wi^T + bi   (bf16 out), N=2048 -> NT=8
    gemm256<DD, 8, 0><<<(M / 256) * 8, 512, 0, stream>>>(
        in_bf, Wi_bf, bi, (void*)u_bf);

    // scan: per-chunk local ends -> carry prefix (in place) -> fix-up + gamma
    scanA<<<dim3(DD / 256, SS, BB), 256, 0, stream>>>(u_bf, plog, Eend);
    scanB<<<(BB * DD) / 256, 256, 0, stream>>>(plog, Eend);
    scanC<<<dim3(DD / 256, SS, BB), 256, 0, stream>>>(u_bf, plog, Eend, xr_bf);

    // GEMM2: out[M, D] = relu(xr[M, 2D] @ Wo^T + bo)  (f32 out), N=1024 -> NT=4
    gemm256<2 * DD, 4, 1><<<(M / 256) * 4, 512, 0, stream>>>(
        xr_bf, Wo_bf, bo, (void*)out);
}